// Round 7
// baseline (101.391 us; speedup 1.0000x reference)
//
#include <hip/hip_runtime.h>
#include <hip/hip_fp16.h>

#define N_NODES 50000
#define K 32
#define NSEL 16
#define D 128
#define DOUT 64
#define NTILES (N_NODES / 16)  // 3125 MFMA node-tiles

typedef __attribute__((ext_vector_type(8))) _Float16 half8;
typedef __attribute__((ext_vector_type(4))) float floatx4;

__device__ __forceinline__ unsigned int pack_h2(float a, float b) {
  union { __half2 h; unsigned int u; } c;
  c.h = __floats2half2_rn(a, b);
  return c.u;
}
__device__ __forceinline__ __half2 as_h2(unsigned int u) {
  union { unsigned int u; __half2 h; } c;
  c.u = u;
  return c.h;
}
__device__ __forceinline__ float fast_tanh(float x) {
  x = fminf(10.f, fmaxf(-10.f, x));
  float e = __expf(2.f * x);
  return (e - 1.f) * __fdividef(1.f, e + 1.f);
}

// Kernel A: mlp2[n] = tanh(feat[n] @ W_mlp + b_mlp) (C=2), feath = fp16(feat).
// TWO nodes per wave: half-wave per node, lane owns dims 4*sub..4*sub+3.
// libm tanhf here — mlp2 feeds top-k selection; fast_tanh flips near-ties.
__global__ __launch_bounds__(256) void mlp_kernel(
    const float* __restrict__ feat, const float* __restrict__ Wm,
    const float* __restrict__ bm, float2* __restrict__ mlp2,
    unsigned int* __restrict__ feath /* [N][D/2] packed half2 */) {
  const int wid = (blockIdx.x * blockDim.x + threadIdx.x) >> 6;  // 0..24999
  const int lane = threadIdx.x & 63;
  const int sub = lane & 31;
  const int n = wid * 2 + (lane >> 5);

  float4 f = *(const float4*)(feat + (size_t)n * D + sub * 4);
  float4 w01 = *(const float4*)(Wm + sub * 8);      // W[4s][0..1],W[4s+1][0..1]
  float4 w23 = *(const float4*)(Wm + sub * 8 + 4);  // W[4s+2][..],W[4s+3][..]
  float p0 = f.x * w01.x + f.y * w01.z + f.z * w23.x + f.w * w23.z;
  float p1 = f.x * w01.y + f.y * w01.w + f.z * w23.y + f.w * w23.w;
#pragma unroll
  for (int off = 16; off; off >>= 1) {  // stays within the 32-lane half
    p0 += __shfl_xor(p0, off);
    p1 += __shfl_xor(p1, off);
  }
  uint2 pk;
  pk.x = pack_h2(f.x, f.y);
  pk.y = pack_h2(f.z, f.w);
  *(uint2*)(feath + n * (D / 2) + sub * 2) = pk;
  if (sub == 0) {
    mlp2[n] = make_float2(tanhf(p0 + bm[0]), tanhf(p1 + bm[1]));
  }
}

// Kernel B: TWO nodes per wave, THREE etypes phase-merged:
//   P1: all srcs + mlp2 gathers up front (6 loads in flight)
//   P2: single rank loop doing all 3 etypes' compares (DS ∥ VALU)
//   P3: single gather loop, 3 independent fp16 row-loads per iteration
// Selection math bit-identical to R4/R6 (top_k tie-break). h stored fp16
// into d_out rows.
__global__ __launch_bounds__(256) void care_kernel(
    const float* __restrict__ feat, const unsigned int* __restrict__ feath,
    const float2* __restrict__ mlp2, const int* __restrict__ nbr0,
    const int* __restrict__ nbr1, const int* __restrict__ nbr2,
    unsigned int* __restrict__ hfw /* aliases d_out; [N][64] words */) {
  const int lane = threadIdx.x & 63;
  const int sub = lane & 31;
  const int hbase = (lane & 32) << 2;  // DS byte addr of this half's lane 0
  const int wid = (blockIdx.x * blockDim.x + threadIdx.x) >> 6;  // 0..24999
  const int n = wid * 2 + (lane >> 5);

  const float2 my = mlp2[n];
  float4 acc = *(const float4*)(feat + (size_t)n * D + sub * 4);  // residual

  // Phase 1: all edge ids + their mlp2 rows
  const int src0 = nbr0[n * K + sub];
  const int src1 = nbr1[n * K + sub];
  const int src2 = nbr2[n * K + sub];
  const float2 mh0 = mlp2[src0];
  const float2 mh1 = mlp2[src1];
  const float2 mh2 = mlp2[src2];
  const float d0 = fabsf(mh0.x - my.x) + fabsf(mh0.y - my.y);
  const float d1 = fabsf(mh1.x - my.x) + fabsf(mh1.y - my.y);
  const float d2 = fabsf(mh2.x - my.x) + fabsf(mh2.y - my.y);

  // Phase 2: rank within half = #{j : d_j < d_i || (d_j == d_i && j < i)}
  int c0 = 0, c1 = 0, c2 = 0;
#pragma unroll
  for (int j = 0; j < K; ++j) {
    float a0 = __int_as_float(
        __builtin_amdgcn_ds_bpermute(hbase + 4 * j, __float_as_int(d0)));
    float a1 = __int_as_float(
        __builtin_amdgcn_ds_bpermute(hbase + 4 * j, __float_as_int(d1)));
    float a2 = __int_as_float(
        __builtin_amdgcn_ds_bpermute(hbase + 4 * j, __float_as_int(d2)));
    c0 += (a0 < d0) || (a0 == d0 && j < sub);
    c1 += (a1 < d1) || (a1 == d1 && j < sub);
    c2 += (a2 < d2) || (a2 == d2 && j < sub);
  }
  // push src to lane hbase/4 + rank; ranks unique per half
  int p0 = __builtin_amdgcn_ds_permute(hbase + (c0 << 2), src0);
  int p1 = __builtin_amdgcn_ds_permute(hbase + (c1 << 2), src1);
  int p2 = __builtin_amdgcn_ds_permute(hbase + (c2 << 2), src2);

  // Phase 3: merged gather — 3 independent row-loads per iteration
  __half2 S00 = as_h2(0u), S01 = as_h2(0u);
  __half2 S10 = as_h2(0u), S11 = as_h2(0u);
  __half2 S20 = as_h2(0u), S21 = as_h2(0u);
#pragma unroll
  for (int t = 0; t < NSEL; ++t) {
    int r0 = __builtin_amdgcn_ds_bpermute(hbase + 4 * t, p0);
    int r1 = __builtin_amdgcn_ds_bpermute(hbase + 4 * t, p1);
    int r2 = __builtin_amdgcn_ds_bpermute(hbase + 4 * t, p2);
    uint2 u0 = *(const uint2*)(feath + (unsigned)(r0 * (D / 2) + sub * 2));
    uint2 u1 = *(const uint2*)(feath + (unsigned)(r1 * (D / 2) + sub * 2));
    uint2 u2 = *(const uint2*)(feath + (unsigned)(r2 * (D / 2) + sub * 2));
    S00 = __hadd2(S00, as_h2(u0.x));
    S01 = __hadd2(S01, as_h2(u0.y));
    S10 = __hadd2(S10, as_h2(u1.x));
    S11 = __hadd2(S11, as_h2(u1.y));
    S20 = __hadd2(S20, as_h2(u2.x));
    S21 = __hadd2(S21, as_h2(u2.y));
  }
  float2 f00 = __half22float2(S00), f01 = __half22float2(S01);
  float2 f10 = __half22float2(S10), f11 = __half22float2(S11);
  float2 f20 = __half22float2(S20), f21 = __half22float2(S21);
  acc.x += 0.5f * fast_tanh(f00.x * (1.f / NSEL));
  acc.y += 0.5f * fast_tanh(f00.y * (1.f / NSEL));
  acc.z += 0.5f * fast_tanh(f01.x * (1.f / NSEL));
  acc.w += 0.5f * fast_tanh(f01.y * (1.f / NSEL));
  acc.x += 0.5f * fast_tanh(f10.x * (1.f / NSEL));
  acc.y += 0.5f * fast_tanh(f10.y * (1.f / NSEL));
  acc.z += 0.5f * fast_tanh(f11.x * (1.f / NSEL));
  acc.w += 0.5f * fast_tanh(f11.y * (1.f / NSEL));
  acc.x += 0.5f * fast_tanh(f20.x * (1.f / NSEL));
  acc.y += 0.5f * fast_tanh(f20.y * (1.f / NSEL));
  acc.z += 0.5f * fast_tanh(f21.x * (1.f / NSEL));
  acc.w += 0.5f * fast_tanh(f21.y * (1.f / NSEL));

  acc.x = fast_tanh(acc.x);
  acc.y = fast_tanh(acc.y);
  acc.z = fast_tanh(acc.z);
  acc.w = fast_tanh(acc.w);
  uint2 p;
  p.x = pack_h2(acc.x, acc.y);
  p.y = pack_h2(acc.z, acc.w);
  *(uint2*)(hfw + n * (D / 2) + sub * 2) = p;  // fp16 h row, 256 B/node
}

// Kernel C: out[50000x64] = h[50000x128] @ W_lin + b_lin via fp16 MFMA.
// h read fp16-packed from d_out rows, overwritten in place (each wave reads
// its full 16-row tile before storing). A: m=lane&15, k=(lane>>4)*8+j.
// C: n=lane&15, m=(lane>>4)*4+reg (m89-verified).
__global__ __launch_bounds__(256) void gemm_kernel(
    const unsigned int* __restrict__ hfw, const float* __restrict__ Wl,
    const float* __restrict__ bl, float* __restrict__ out) {
  __shared__ _Float16 sB[16 * 64 * 8];  // 16 KB: [kk*4+nt][lane][8]

  for (int w = threadIdx.x; w < 4096; w += blockDim.x) {
    int f = w >> 8, l = (w >> 2) & 63, j2 = w & 3;
    int kk = f >> 2, nt = f & 3;
    int k = kk * 32 + ((l >> 4) << 3) + 2 * j2;
    int nn = nt * 16 + (l & 15);
    ((unsigned int*)sB)[w] = pack_h2(Wl[k * DOUT + nn], Wl[(k + 1) * DOUT + nn]);
  }
  __syncthreads();

  const int lane = threadIdx.x & 63;
  const int tile = blockIdx.x * 4 + (threadIdx.x >> 6);
  if (tile >= NTILES) return;
  const int m0 = tile * 16;

  floatx4 acc[4];
#pragma unroll
  for (int nt = 0; nt < 4; ++nt) {
    float bn = bl[nt * 16 + (lane & 15)];
    acc[nt] = (floatx4){bn, bn, bn, bn};
  }
  const _Float16* hf = (const _Float16*)hfw;
#pragma unroll
  for (int kk = 0; kk < 4; ++kk) {
    half8 a = *(const half8*)(hf + (size_t)(m0 + (lane & 15)) * D + kk * 32 +
                              ((lane >> 4) << 3));
#pragma unroll
    for (int nt = 0; nt < 4; ++nt) {
      half8 bfr = *(const half8*)(sB + ((kk * 4 + nt) * 64 + lane) * 8);
      acc[nt] = __builtin_amdgcn_mfma_f32_16x16x32_f16(a, bfr, acc[nt], 0, 0, 0);
    }
  }
#pragma unroll
  for (int nt = 0; nt < 4; ++nt) {
#pragma unroll
    for (int r = 0; r < 4; ++r) {
      int m = m0 + ((lane >> 4) << 2) + r;
      out[(size_t)m * DOUT + nt * 16 + (lane & 15)] = acc[nt][r];
    }
  }
}

extern "C" void kernel_launch(void* const* d_in, const int* in_sizes, int n_in,
                              void* d_out, int out_size, void* d_ws,
                              size_t ws_size, hipStream_t stream) {
  const float* feat = (const float*)d_in[0];
  const float* Wm = (const float*)d_in[1];
  const float* bm = (const float*)d_in[2];
  const float* Wl = (const float*)d_in[3];
  const float* bl = (const float*)d_in[4];
  const int* nbr0 = (const int*)d_in[5];
  const int* nbr1 = (const int*)d_in[6];
  const int* nbr2 = (const int*)d_in[7];
  float* out = (float*)d_out;
  float2* mlp2 = (float2*)d_ws;                                      // 400 KB
  unsigned int* feath = (unsigned int*)((char*)d_ws + (512 << 10));  // 12.8 MB

  mlp_kernel<<<N_NODES / 8, 256, 0, stream>>>(feat, Wm, bm, mlp2, feath);
  care_kernel<<<N_NODES / 8, 256, 0, stream>>>(feat, feath, mlp2, nbr0, nbr1,
                                               nbr2, (unsigned int*)d_out);
  gemm_kernel<<<(NTILES + 3) / 4, 256, 0, stream>>>((const unsigned int*)d_out,
                                                    Wl, bl, out);
}

// Round 8
// 101.178 us; speedup vs baseline: 1.0021x; 1.0021x over previous
//
#include <hip/hip_runtime.h>
#include <hip/hip_fp16.h>

#define N_NODES 50000
#define K 32
#define NSEL 16
#define D 128
#define DOUT 64
#define NTILES (N_NODES / 16)  // 3125 MFMA node-tiles

typedef __attribute__((ext_vector_type(8))) _Float16 half8;
typedef __attribute__((ext_vector_type(4))) float floatx4;

__device__ __forceinline__ unsigned int pack_h2(float a, float b) {
  union { __half2 h; unsigned int u; } c;
  c.h = __floats2half2_rn(a, b);
  return c.u;
}
__device__ __forceinline__ __half2 as_h2(unsigned int u) {
  union { unsigned int u; __half2 h; } c;
  c.u = u;
  return c.h;
}
__device__ __forceinline__ float fast_tanh(float x) {
  x = fminf(10.f, fmaxf(-10.f, x));
  float e = __expf(2.f * x);
  return (e - 1.f) * __fdividef(1.f, e + 1.f);
}

// DPP row-rotate-right by literal N within 16-lane rows (VALU pipe, no DS).
#define ROR(x, N) __builtin_amdgcn_update_dpp(0, (x), 0x120 + (N), 0xF, 0xF, true)
// ds_swizzle lane^16 (swap 16-rows within each 32-lane half): offset=0x401F
#define SWAP16(x) __builtin_amdgcn_ds_swizzle((x), 0x401F)

// Kernel A: mlp2[n] = tanh(feat[n] @ W_mlp + b_mlp) (C=2), feath = fp16(feat).
// TWO nodes per wave. libm tanhf — mlp2 feeds top-k; fast_tanh flips ties.
__global__ __launch_bounds__(256) void mlp_kernel(
    const float* __restrict__ feat, const float* __restrict__ Wm,
    const float* __restrict__ bm, float2* __restrict__ mlp2,
    unsigned int* __restrict__ feath /* [N][D/2] packed half2 */) {
  const int wid = (blockIdx.x * blockDim.x + threadIdx.x) >> 6;  // 0..24999
  const int lane = threadIdx.x & 63;
  const int sub = lane & 31;
  const int n = wid * 2 + (lane >> 5);

  float4 f = *(const float4*)(feat + (size_t)n * D + sub * 4);
  float4 w01 = *(const float4*)(Wm + sub * 8);
  float4 w23 = *(const float4*)(Wm + sub * 8 + 4);
  float p0 = f.x * w01.x + f.y * w01.z + f.z * w23.x + f.w * w23.z;
  float p1 = f.x * w01.y + f.y * w01.w + f.z * w23.y + f.w * w23.w;
#pragma unroll
  for (int off = 16; off; off >>= 1) {  // stays within the 32-lane half
    p0 += __shfl_xor(p0, off);
    p1 += __shfl_xor(p1, off);
  }
  uint2 pk;
  pk.x = pack_h2(f.x, f.y);
  pk.y = pack_h2(f.z, f.w);
  *(uint2*)(feath + n * (D / 2) + sub * 2) = pk;
  if (sub == 0) {
    mlp2[n] = make_float2(tanhf(p0 + bm[0]), tanhf(p1 + bm[1]));
  }
}

// Kernel B: TWO nodes per wave, 3 etypes merged. Rank via DPP rotations
// (no DS in the compare loop); tie-break exact & direction-proof (rotated
// index vector gives true source j). Gather via ds_permute/bpermute + fp16
// row loads. h stored fp16 into d_out rows.
__global__ __launch_bounds__(256) void care_kernel(
    const float* __restrict__ feat, const unsigned int* __restrict__ feath,
    const float2* __restrict__ mlp2, const int* __restrict__ nbr0,
    const int* __restrict__ nbr1, const int* __restrict__ nbr2,
    unsigned int* __restrict__ hfw /* aliases d_out; [N][64] words */) {
  const int lane = threadIdx.x & 63;
  const int sub = lane & 31;
  const int hbase = (lane & 32) << 2;  // DS byte addr of this half's lane 0
  const int wid = (blockIdx.x * blockDim.x + threadIdx.x) >> 6;  // 0..24999
  const int n = wid * 2 + (lane >> 5);

  const float2 my = mlp2[n];
  float4 acc = *(const float4*)(feat + (size_t)n * D + sub * 4);  // residual

  // Phase 1: all edge ids + their mlp2 rows (6 loads in flight)
  const int src0 = nbr0[n * K + sub];
  const int src1 = nbr1[n * K + sub];
  const int src2 = nbr2[n * K + sub];
  const float2 mh0 = mlp2[src0];
  const float2 mh1 = mlp2[src1];
  const float2 mh2 = mlp2[src2];
  const float d0 = fabsf(mh0.x - my.x) + fabsf(mh0.y - my.y);
  const float d1 = fabsf(mh1.x - my.x) + fabsf(mh1.y - my.y);
  const float d2 = fabsf(mh2.x - my.x) + fabsf(mh2.y - my.y);

  // Phase 2: rank = #{j : d_j < d_i || (d_j == d_i && j < i)} within half.
  // 15 within-row rotations + row-swap + 16 rotations of the swapped copy.
  const int b0 = __float_as_int(d0);
  const int b1 = __float_as_int(d1);
  const int b2 = __float_as_int(d2);
  const int s0 = SWAP16(b0);
  const int s1 = SWAP16(b1);
  const int s2 = SWAP16(b2);
  const int jsw = SWAP16(sub);  // = sub ^ 16
  int c0 = 0, c1 = 0, c2 = 0;

#define CMP3(aj0, aj1, aj2, jr)                                  \
  {                                                              \
    const float A0 = __int_as_float(aj0);                        \
    const float A1 = __int_as_float(aj1);                        \
    const float A2 = __int_as_float(aj2);                        \
    const bool tb = (jr) < sub;                                  \
    c0 += (A0 < d0) || (A0 == d0 && tb);                         \
    c1 += (A1 < d1) || (A1 == d1 && tb);                         \
    c2 += (A2 < d2) || (A2 == d2 && tb);                         \
  }
#define STEP_P(r) CMP3(ROR(b0, r), ROR(b1, r), ROR(b2, r), ROR(sub, r))
#define STEP_S(r) CMP3(ROR(s0, r), ROR(s1, r), ROR(s2, r), ROR(jsw, r))

  STEP_P(1)  STEP_P(2)  STEP_P(3)  STEP_P(4)  STEP_P(5)
  STEP_P(6)  STEP_P(7)  STEP_P(8)  STEP_P(9)  STEP_P(10)
  STEP_P(11) STEP_P(12) STEP_P(13) STEP_P(14) STEP_P(15)
  CMP3(s0, s1, s2, jsw)  // swapped copy, rotation 0
  STEP_S(1)  STEP_S(2)  STEP_S(3)  STEP_S(4)  STEP_S(5)
  STEP_S(6)  STEP_S(7)  STEP_S(8)  STEP_S(9)  STEP_S(10)
  STEP_S(11) STEP_S(12) STEP_S(13) STEP_S(14) STEP_S(15)
#undef STEP_S
#undef STEP_P
#undef CMP3

  // push src to lane hbase/4 + rank; ranks unique per half
  int p0 = __builtin_amdgcn_ds_permute(hbase + (c0 << 2), src0);
  int p1 = __builtin_amdgcn_ds_permute(hbase + (c1 << 2), src1);
  int p2 = __builtin_amdgcn_ds_permute(hbase + (c2 << 2), src2);

  // Phase 3: merged gather — 3 independent fp16 row-loads per iteration
  __half2 S00 = as_h2(0u), S01 = as_h2(0u);
  __half2 S10 = as_h2(0u), S11 = as_h2(0u);
  __half2 S20 = as_h2(0u), S21 = as_h2(0u);
#pragma unroll
  for (int t = 0; t < NSEL; ++t) {
    int r0 = __builtin_amdgcn_ds_bpermute(hbase + 4 * t, p0);
    int r1 = __builtin_amdgcn_ds_bpermute(hbase + 4 * t, p1);
    int r2 = __builtin_amdgcn_ds_bpermute(hbase + 4 * t, p2);
    uint2 u0 = *(const uint2*)(feath + (unsigned)(r0 * (D / 2) + sub * 2));
    uint2 u1 = *(const uint2*)(feath + (unsigned)(r1 * (D / 2) + sub * 2));
    uint2 u2 = *(const uint2*)(feath + (unsigned)(r2 * (D / 2) + sub * 2));
    S00 = __hadd2(S00, as_h2(u0.x));
    S01 = __hadd2(S01, as_h2(u0.y));
    S10 = __hadd2(S10, as_h2(u1.x));
    S11 = __hadd2(S11, as_h2(u1.y));
    S20 = __hadd2(S20, as_h2(u2.x));
    S21 = __hadd2(S21, as_h2(u2.y));
  }
  float2 f00 = __half22float2(S00), f01 = __half22float2(S01);
  float2 f10 = __half22float2(S10), f11 = __half22float2(S11);
  float2 f20 = __half22float2(S20), f21 = __half22float2(S21);
  acc.x += 0.5f * fast_tanh(f00.x * (1.f / NSEL));
  acc.y += 0.5f * fast_tanh(f00.y * (1.f / NSEL));
  acc.z += 0.5f * fast_tanh(f01.x * (1.f / NSEL));
  acc.w += 0.5f * fast_tanh(f01.y * (1.f / NSEL));
  acc.x += 0.5f * fast_tanh(f10.x * (1.f / NSEL));
  acc.y += 0.5f * fast_tanh(f10.y * (1.f / NSEL));
  acc.z += 0.5f * fast_tanh(f11.x * (1.f / NSEL));
  acc.w += 0.5f * fast_tanh(f11.y * (1.f / NSEL));
  acc.x += 0.5f * fast_tanh(f20.x * (1.f / NSEL));
  acc.y += 0.5f * fast_tanh(f20.y * (1.f / NSEL));
  acc.z += 0.5f * fast_tanh(f21.x * (1.f / NSEL));
  acc.w += 0.5f * fast_tanh(f21.y * (1.f / NSEL));

  acc.x = fast_tanh(acc.x);
  acc.y = fast_tanh(acc.y);
  acc.z = fast_tanh(acc.z);
  acc.w = fast_tanh(acc.w);
  uint2 p;
  p.x = pack_h2(acc.x, acc.y);
  p.y = pack_h2(acc.z, acc.w);
  *(uint2*)(hfw + n * (D / 2) + sub * 2) = p;  // fp16 h row, 256 B/node
}

// Kernel C: out[50000x64] = h[50000x128] @ W_lin + b_lin via fp16 MFMA.
// h read fp16-packed from d_out rows, overwritten in place (each wave reads
// its full 16-row tile before storing). A: m=lane&15, k=(lane>>4)*8+j.
// C: n=lane&15, m=(lane>>4)*4+reg (m89-verified).
__global__ __launch_bounds__(256) void gemm_kernel(
    const unsigned int* __restrict__ hfw, const float* __restrict__ Wl,
    const float* __restrict__ bl, float* __restrict__ out) {
  __shared__ _Float16 sB[16 * 64 * 8];  // 16 KB: [kk*4+nt][lane][8]

  for (int w = threadIdx.x; w < 4096; w += blockDim.x) {
    int f = w >> 8, l = (w >> 2) & 63, j2 = w & 3;
    int kk = f >> 2, nt = f & 3;
    int k = kk * 32 + ((l >> 4) << 3) + 2 * j2;
    int nn = nt * 16 + (l & 15);
    ((unsigned int*)sB)[w] = pack_h2(Wl[k * DOUT + nn], Wl[(k + 1) * DOUT + nn]);
  }
  __syncthreads();

  const int lane = threadIdx.x & 63;
  const int tile = blockIdx.x * 4 + (threadIdx.x >> 6);
  if (tile >= NTILES) return;
  const int m0 = tile * 16;

  floatx4 acc[4];
#pragma unroll
  for (int nt = 0; nt < 4; ++nt) {
    float bn = bl[nt * 16 + (lane & 15)];
    acc[nt] = (floatx4){bn, bn, bn, bn};
  }
  const _Float16* hf = (const _Float16*)hfw;
#pragma unroll
  for (int kk = 0; kk < 4; ++kk) {
    half8 a = *(const half8*)(hf + (size_t)(m0 + (lane & 15)) * D + kk * 32 +
                              ((lane >> 4) << 3));
#pragma unroll
    for (int nt = 0; nt < 4; ++nt) {
      half8 bfr = *(const half8*)(sB + ((kk * 4 + nt) * 64 + lane) * 8);
      acc[nt] = __builtin_amdgcn_mfma_f32_16x16x32_f16(a, bfr, acc[nt], 0, 0, 0);
    }
  }
#pragma unroll
  for (int nt = 0; nt < 4; ++nt) {
#pragma unroll
    for (int r = 0; r < 4; ++r) {
      int m = m0 + ((lane >> 4) << 2) + r;
      out[(size_t)m * DOUT + nt * 16 + (lane & 15)] = acc[nt][r];
    }
  }
}

extern "C" void kernel_launch(void* const* d_in, const int* in_sizes, int n_in,
                              void* d_out, int out_size, void* d_ws,
                              size_t ws_size, hipStream_t stream) {
  const float* feat = (const float*)d_in[0];
  const float* Wm = (const float*)d_in[1];
  const float* bm = (const float*)d_in[2];
  const float* Wl = (const float*)d_in[3];
  const float* bl = (const float*)d_in[4];
  const int* nbr0 = (const int*)d_in[5];
  const int* nbr1 = (const int*)d_in[6];
  const int* nbr2 = (const int*)d_in[7];
  float* out = (float*)d_out;
  float2* mlp2 = (float2*)d_ws;                                      // 400 KB
  unsigned int* feath = (unsigned int*)((char*)d_ws + (512 << 10));  // 12.8 MB

  mlp_kernel<<<N_NODES / 8, 256, 0, stream>>>(feat, Wm, bm, mlp2, feath);
  care_kernel<<<N_NODES / 8, 256, 0, stream>>>(feat, feath, mlp2, nbr0, nbr1,
                                               nbr2, (unsigned int*)d_out);
  gemm_kernel<<<(NTILES + 3) / 4, 256, 0, stream>>>((const unsigned int*)d_out,
                                                    Wl, bl, out);
}

// Round 9
// 101.155 us; speedup vs baseline: 1.0023x; 1.0002x over previous
//
#include <hip/hip_runtime.h>
#include <hip/hip_fp16.h>

#define N_NODES 50000
#define K 32
#define NSEL 16
#define D 128
#define DOUT 64
#define NTILES (N_NODES / 16)  // 3125 MFMA node-tiles

typedef __attribute__((ext_vector_type(8))) _Float16 half8;
typedef __attribute__((ext_vector_type(4))) float floatx4;

__device__ __forceinline__ unsigned int pack_h2(float a, float b) {
  union { __half2 h; unsigned int u; } c;
  c.h = __floats2half2_rn(a, b);
  return c.u;
}
__device__ __forceinline__ __half2 as_h2(unsigned int u) {
  union { unsigned int u; __half2 h; } c;
  c.u = u;
  return c.h;
}
__device__ __forceinline__ float fast_tanh(float x) {
  x = fminf(10.f, fmaxf(-10.f, x));
  float e = __expf(2.f * x);
  return (e - 1.f) * __fdividef(1.f, e + 1.f);
}

// DPP row-rotate-right by literal N within 16-lane rows (VALU pipe, no DS).
#define ROR(x, N) __builtin_amdgcn_update_dpp(0, (x), 0x120 + (N), 0xF, 0xF, true)
// ds_swizzle lane^16 (swap 16-rows within each 32-lane half): offset=0x401F
#define SWAP16(x) __builtin_amdgcn_ds_swizzle((x), 0x401F)

// Kernel A: mlp2[n] = tanh(feat[n] @ W_mlp + b_mlp) (C=2), feath = fp16(feat).
// TWO nodes per wave. libm tanhf — mlp2 feeds top-k; fast_tanh flips ties.
__global__ __launch_bounds__(256) void mlp_kernel(
    const float* __restrict__ feat, const float* __restrict__ Wm,
    const float* __restrict__ bm, float2* __restrict__ mlp2,
    unsigned int* __restrict__ feath /* [N][D/2] packed half2 */) {
  const int wid = (blockIdx.x * blockDim.x + threadIdx.x) >> 6;  // 0..24999
  const int lane = threadIdx.x & 63;
  const int sub = lane & 31;
  const int n = wid * 2 + (lane >> 5);

  float4 f = *(const float4*)(feat + (size_t)n * D + sub * 4);
  float4 w01 = *(const float4*)(Wm + sub * 8);
  float4 w23 = *(const float4*)(Wm + sub * 8 + 4);
  float p0 = f.x * w01.x + f.y * w01.z + f.z * w23.x + f.w * w23.z;
  float p1 = f.x * w01.y + f.y * w01.w + f.z * w23.y + f.w * w23.w;
#pragma unroll
  for (int off = 16; off; off >>= 1) {  // stays within the 32-lane half
    p0 += __shfl_xor(p0, off);
    p1 += __shfl_xor(p1, off);
  }
  uint2 pk;
  pk.x = pack_h2(f.x, f.y);
  pk.y = pack_h2(f.z, f.w);
  *(uint2*)(feath + n * (D / 2) + sub * 2) = pk;
  if (sub == 0) {
    mlp2[n] = make_float2(tanhf(p0 + bm[0]), tanhf(p1 + bm[1]));
  }
}

// Kernel B: TWO nodes per wave, 3 etypes merged. Rank via DPP rotations.
// Gather: 2 batches of 24 independent dwordx2 loads (deep MLP, reg-staged).
// Selection math + accumulation order bit-identical to R8. h stored fp16
// into d_out rows. launch_bounds(256,4): allow ~128 VGPR for load batching.
__global__ __launch_bounds__(256, 4) void care_kernel(
    const float* __restrict__ feat, const unsigned int* __restrict__ feath,
    const float2* __restrict__ mlp2, const int* __restrict__ nbr0,
    const int* __restrict__ nbr1, const int* __restrict__ nbr2,
    unsigned int* __restrict__ hfw /* aliases d_out; [N][64] words */) {
  const int lane = threadIdx.x & 63;
  const int sub = lane & 31;
  const int hbase = (lane & 32) << 2;  // DS byte addr of this half's lane 0
  const int wid = (blockIdx.x * blockDim.x + threadIdx.x) >> 6;  // 0..24999
  const int n = wid * 2 + (lane >> 5);

  const float2 my = mlp2[n];
  float4 acc = *(const float4*)(feat + (size_t)n * D + sub * 4);  // residual

  // Phase 1: all edge ids + their mlp2 rows (6 loads in flight)
  const int src0 = nbr0[n * K + sub];
  const int src1 = nbr1[n * K + sub];
  const int src2 = nbr2[n * K + sub];
  const float2 mh0 = mlp2[src0];
  const float2 mh1 = mlp2[src1];
  const float2 mh2 = mlp2[src2];
  const float d0 = fabsf(mh0.x - my.x) + fabsf(mh0.y - my.y);
  const float d1 = fabsf(mh1.x - my.x) + fabsf(mh1.y - my.y);
  const float d2 = fabsf(mh2.x - my.x) + fabsf(mh2.y - my.y);

  // Phase 2: rank = #{j : d_j < d_i || (d_j == d_i && j < i)} within half.
  const int b0 = __float_as_int(d0);
  const int b1 = __float_as_int(d1);
  const int b2 = __float_as_int(d2);
  const int s0 = SWAP16(b0);
  const int s1 = SWAP16(b1);
  const int s2 = SWAP16(b2);
  const int jsw = SWAP16(sub);  // = sub ^ 16
  int c0 = 0, c1 = 0, c2 = 0;

#define CMP3(aj0, aj1, aj2, jr)                                  \
  {                                                              \
    const float A0 = __int_as_float(aj0);                        \
    const float A1 = __int_as_float(aj1);                        \
    const float A2 = __int_as_float(aj2);                        \
    const bool tb = (jr) < sub;                                  \
    c0 += (A0 < d0) || (A0 == d0 && tb);                         \
    c1 += (A1 < d1) || (A1 == d1 && tb);                         \
    c2 += (A2 < d2) || (A2 == d2 && tb);                         \
  }
#define STEP_P(r) CMP3(ROR(b0, r), ROR(b1, r), ROR(b2, r), ROR(sub, r))
#define STEP_S(r) CMP3(ROR(s0, r), ROR(s1, r), ROR(s2, r), ROR(jsw, r))

  STEP_P(1)  STEP_P(2)  STEP_P(3)  STEP_P(4)  STEP_P(5)
  STEP_P(6)  STEP_P(7)  STEP_P(8)  STEP_P(9)  STEP_P(10)
  STEP_P(11) STEP_P(12) STEP_P(13) STEP_P(14) STEP_P(15)
  CMP3(s0, s1, s2, jsw)  // swapped copy, rotation 0
  STEP_S(1)  STEP_S(2)  STEP_S(3)  STEP_S(4)  STEP_S(5)
  STEP_S(6)  STEP_S(7)  STEP_S(8)  STEP_S(9)  STEP_S(10)
  STEP_S(11) STEP_S(12) STEP_S(13) STEP_S(14) STEP_S(15)
#undef STEP_S
#undef STEP_P
#undef CMP3

  // push src to lane hbase/4 + rank; ranks unique per half
  int p0 = __builtin_amdgcn_ds_permute(hbase + (c0 << 2), src0);
  int p1 = __builtin_amdgcn_ds_permute(hbase + (c1 << 2), src1);
  int p2 = __builtin_amdgcn_ds_permute(hbase + (c2 << 2), src2);

  // Phase 3: gather in 2 batches of 24 independent loads (deep pipelining).
  // Accumulation order per etype stays t = 0..15 sequential (bit-identical).
  __half2 S00 = as_h2(0u), S01 = as_h2(0u);
  __half2 S10 = as_h2(0u), S11 = as_h2(0u);
  __half2 S20 = as_h2(0u), S21 = as_h2(0u);
#pragma unroll 1
  for (int b = 0; b < 2; ++b) {
    uint2 u0[8], u1[8], u2[8];
#pragma unroll
    for (int t = 0; t < 8; ++t) {
      const int tt = b * 8 + t;
      int r0 = __builtin_amdgcn_ds_bpermute(hbase + 4 * tt, p0);
      int r1 = __builtin_amdgcn_ds_bpermute(hbase + 4 * tt, p1);
      int r2 = __builtin_amdgcn_ds_bpermute(hbase + 4 * tt, p2);
      u0[t] = *(const uint2*)(feath + (unsigned)(r0 * (D / 2) + sub * 2));
      u1[t] = *(const uint2*)(feath + (unsigned)(r1 * (D / 2) + sub * 2));
      u2[t] = *(const uint2*)(feath + (unsigned)(r2 * (D / 2) + sub * 2));
    }
#pragma unroll
    for (int t = 0; t < 8; ++t) {
      S00 = __hadd2(S00, as_h2(u0[t].x));
      S01 = __hadd2(S01, as_h2(u0[t].y));
      S10 = __hadd2(S10, as_h2(u1[t].x));
      S11 = __hadd2(S11, as_h2(u1[t].y));
      S20 = __hadd2(S20, as_h2(u2[t].x));
      S21 = __hadd2(S21, as_h2(u2[t].y));
    }
  }
  float2 f00 = __half22float2(S00), f01 = __half22float2(S01);
  float2 f10 = __half22float2(S10), f11 = __half22float2(S11);
  float2 f20 = __half22float2(S20), f21 = __half22float2(S21);
  acc.x += 0.5f * fast_tanh(f00.x * (1.f / NSEL));
  acc.y += 0.5f * fast_tanh(f00.y * (1.f / NSEL));
  acc.z += 0.5f * fast_tanh(f01.x * (1.f / NSEL));
  acc.w += 0.5f * fast_tanh(f01.y * (1.f / NSEL));
  acc.x += 0.5f * fast_tanh(f10.x * (1.f / NSEL));
  acc.y += 0.5f * fast_tanh(f10.y * (1.f / NSEL));
  acc.z += 0.5f * fast_tanh(f11.x * (1.f / NSEL));
  acc.w += 0.5f * fast_tanh(f11.y * (1.f / NSEL));
  acc.x += 0.5f * fast_tanh(f20.x * (1.f / NSEL));
  acc.y += 0.5f * fast_tanh(f20.y * (1.f / NSEL));
  acc.z += 0.5f * fast_tanh(f21.x * (1.f / NSEL));
  acc.w += 0.5f * fast_tanh(f21.y * (1.f / NSEL));

  acc.x = fast_tanh(acc.x);
  acc.y = fast_tanh(acc.y);
  acc.z = fast_tanh(acc.z);
  acc.w = fast_tanh(acc.w);
  uint2 p;
  p.x = pack_h2(acc.x, acc.y);
  p.y = pack_h2(acc.z, acc.w);
  *(uint2*)(hfw + n * (D / 2) + sub * 2) = p;  // fp16 h row, 256 B/node
}

// Kernel C: out[50000x64] = h[50000x128] @ W_lin + b_lin via fp16 MFMA.
// h read fp16-packed from d_out rows, overwritten in place (each wave reads
// its full 16-row tile before storing). A: m=lane&15, k=(lane>>4)*8+j.
// C: n=lane&15, m=(lane>>4)*4+reg (m89-verified).
__global__ __launch_bounds__(256) void gemm_kernel(
    const unsigned int* __restrict__ hfw, const float* __restrict__ Wl,
    const float* __restrict__ bl, float* __restrict__ out) {
  __shared__ _Float16 sB[16 * 64 * 8];  // 16 KB: [kk*4+nt][lane][8]

  for (int w = threadIdx.x; w < 4096; w += blockDim.x) {
    int f = w >> 8, l = (w >> 2) & 63, j2 = w & 3;
    int kk = f >> 2, nt = f & 3;
    int k = kk * 32 + ((l >> 4) << 3) + 2 * j2;
    int nn = nt * 16 + (l & 15);
    ((unsigned int*)sB)[w] = pack_h2(Wl[k * DOUT + nn], Wl[(k + 1) * DOUT + nn]);
  }
  __syncthreads();

  const int lane = threadIdx.x & 63;
  const int tile = blockIdx.x * 4 + (threadIdx.x >> 6);
  if (tile >= NTILES) return;
  const int m0 = tile * 16;

  floatx4 acc[4];
#pragma unroll
  for (int nt = 0; nt < 4; ++nt) {
    float bn = bl[nt * 16 + (lane & 15)];
    acc[nt] = (floatx4){bn, bn, bn, bn};
  }
  const _Float16* hf = (const _Float16*)hfw;
#pragma unroll
  for (int kk = 0; kk < 4; ++kk) {
    half8 a = *(const half8*)(hf + (size_t)(m0 + (lane & 15)) * D + kk * 32 +
                              ((lane >> 4) << 3));
#pragma unroll
    for (int nt = 0; nt < 4; ++nt) {
      half8 bfr = *(const half8*)(sB + ((kk * 4 + nt) * 64 + lane) * 8);
      acc[nt] = __builtin_amdgcn_mfma_f32_16x16x32_f16(a, bfr, acc[nt], 0, 0, 0);
    }
  }
#pragma unroll
  for (int nt = 0; nt < 4; ++nt) {
#pragma unroll
    for (int r = 0; r < 4; ++r) {
      int m = m0 + ((lane >> 4) << 2) + r;
      out[(size_t)m * DOUT + nt * 16 + (lane & 15)] = acc[nt][r];
    }
  }
}

extern "C" void kernel_launch(void* const* d_in, const int* in_sizes, int n_in,
                              void* d_out, int out_size, void* d_ws,
                              size_t ws_size, hipStream_t stream) {
  const float* feat = (const float*)d_in[0];
  const float* Wm = (const float*)d_in[1];
  const float* bm = (const float*)d_in[2];
  const float* Wl = (const float*)d_in[3];
  const float* bl = (const float*)d_in[4];
  const int* nbr0 = (const int*)d_in[5];
  const int* nbr1 = (const int*)d_in[6];
  const int* nbr2 = (const int*)d_in[7];
  float* out = (float*)d_out;
  float2* mlp2 = (float2*)d_ws;                                      // 400 KB
  unsigned int* feath = (unsigned int*)((char*)d_ws + (512 << 10));  // 12.8 MB

  mlp_kernel<<<N_NODES / 8, 256, 0, stream>>>(feat, Wm, bm, mlp2, feath);
  care_kernel<<<N_NODES / 8, 256, 0, stream>>>(feat, feath, mlp2, nbr0, nbr1,
                                               nbr2, (unsigned int*)d_out);
  gemm_kernel<<<(NTILES + 3) / 4, 256, 0, stream>>>((const unsigned int*)d_out,
                                                    Wl, bl, out);
}

// Round 10
// 75.071 us; speedup vs baseline: 1.3506x; 1.3475x over previous
//
#include <hip/hip_runtime.h>
#include <hip/hip_fp16.h>

#define N_NODES 50000
#define K 32
#define NSEL 16
#define D 128
#define DOUT 64
#define NTILES (N_NODES / 16)  // 3125 MFMA node-tiles

typedef __attribute__((ext_vector_type(8))) _Float16 half8;
typedef __attribute__((ext_vector_type(4))) float floatx4;
typedef __attribute__((ext_vector_type(2))) float floatx2;

__device__ __forceinline__ unsigned int pack_h2(float a, float b) {
  union { __half2 h; unsigned int u; } c;
  c.h = __floats2half2_rn(a, b);
  return c.u;
}
__device__ __forceinline__ float fast_tanh(float x) {
  x = fminf(10.f, fmaxf(-10.f, x));
  float e = __expf(2.f * x);
  return (e - 1.f) * __fdividef(1.f, e + 1.f);
}

// DPP row-rotate-right by literal N within 16-lane rows (VALU pipe, no DS).
#define ROR(x, N) __builtin_amdgcn_update_dpp(0, (x), 0x120 + (N), 0xF, 0xF, true)
// ds_swizzle lane^16 (swap 16-rows within each 32-lane half): offset=0x401F
#define SWAP16(x) __builtin_amdgcn_ds_swizzle((x), 0x401F)

// Kernel A: mlp2[n] = tanh(feat[n] @ W_mlp + b_mlp) (C=2), feat8 = fp8(feat).
// TWO nodes per wave. libm tanhf — mlp2 feeds top-k; fast_tanh flips ties.
__global__ __launch_bounds__(256) void mlp_kernel(
    const float* __restrict__ feat, const float* __restrict__ Wm,
    const float* __restrict__ bm, float2* __restrict__ mlp2,
    unsigned char* __restrict__ feat8 /* [N][D] fp8 e4m3, 128 B rows */) {
  const int wid = (blockIdx.x * blockDim.x + threadIdx.x) >> 6;  // 0..24999
  const int lane = threadIdx.x & 63;
  const int sub = lane & 31;
  const int n = wid * 2 + (lane >> 5);

  float4 f = *(const float4*)(feat + (size_t)n * D + sub * 4);
  float4 w01 = *(const float4*)(Wm + sub * 8);
  float4 w23 = *(const float4*)(Wm + sub * 8 + 4);
  float p0 = f.x * w01.x + f.y * w01.z + f.z * w23.x + f.w * w23.z;
  float p1 = f.x * w01.y + f.y * w01.w + f.z * w23.y + f.w * w23.w;
#pragma unroll
  for (int off = 16; off; off >>= 1) {  // stays within the 32-lane half
    p0 += __shfl_xor(p0, off);
    p1 += __shfl_xor(p1, off);
  }
  // fp8 e4m3 copy of feat (RNE pack, 4 dims -> 1 dword per lane)
  int pk8 = __builtin_amdgcn_cvt_pk_fp8_f32(f.x, f.y, 0, false);
  pk8 = __builtin_amdgcn_cvt_pk_fp8_f32(f.z, f.w, pk8, true);
  *(unsigned int*)(feat8 + ((size_t)n << 7) + (sub << 2)) = (unsigned int)pk8;
  if (sub == 0) {
    mlp2[n] = make_float2(tanhf(p0 + bm[0]), tanhf(p1 + bm[1]));
  }
}

// Kernel B: TWO nodes per wave, 3 etypes merged. Rank via DPP rotations
// (bit-exact top_k tie-break). Gather reads fp8 rows (128 B — 6.4 MB total,
// ~62% per-XCD L2 resident) and accumulates in f32. h stored fp16 into
// d_out rows.
__global__ __launch_bounds__(256) void care_kernel(
    const float* __restrict__ feat, const unsigned char* __restrict__ feat8,
    const float2* __restrict__ mlp2, const int* __restrict__ nbr0,
    const int* __restrict__ nbr1, const int* __restrict__ nbr2,
    unsigned int* __restrict__ hfw /* aliases d_out; [N][64] words */) {
  const int lane = threadIdx.x & 63;
  const int sub = lane & 31;
  const int hbase = (lane & 32) << 2;  // DS byte addr of this half's lane 0
  const int wid = (blockIdx.x * blockDim.x + threadIdx.x) >> 6;  // 0..24999
  const int n = wid * 2 + (lane >> 5);

  const float2 my = mlp2[n];
  float4 acc = *(const float4*)(feat + (size_t)n * D + sub * 4);  // residual

  // Phase 1: all edge ids + their mlp2 rows (6 loads in flight)
  const int src0 = nbr0[n * K + sub];
  const int src1 = nbr1[n * K + sub];
  const int src2 = nbr2[n * K + sub];
  const float2 mh0 = mlp2[src0];
  const float2 mh1 = mlp2[src1];
  const float2 mh2 = mlp2[src2];
  const float d0 = fabsf(mh0.x - my.x) + fabsf(mh0.y - my.y);
  const float d1 = fabsf(mh1.x - my.x) + fabsf(mh1.y - my.y);
  const float d2 = fabsf(mh2.x - my.x) + fabsf(mh2.y - my.y);

  // Phase 2: rank = #{j : d_j < d_i || (d_j == d_i && j < i)} within half.
  const int b0 = __float_as_int(d0);
  const int b1 = __float_as_int(d1);
  const int b2 = __float_as_int(d2);
  const int s0 = SWAP16(b0);
  const int s1 = SWAP16(b1);
  const int s2 = SWAP16(b2);
  const int jsw = SWAP16(sub);  // = sub ^ 16
  int c0 = 0, c1 = 0, c2 = 0;

#define CMP3(aj0, aj1, aj2, jr)                                  \
  {                                                              \
    const float A0 = __int_as_float(aj0);                        \
    const float A1 = __int_as_float(aj1);                        \
    const float A2 = __int_as_float(aj2);                        \
    const bool tb = (jr) < sub;                                  \
    c0 += (A0 < d0) || (A0 == d0 && tb);                         \
    c1 += (A1 < d1) || (A1 == d1 && tb);                         \
    c2 += (A2 < d2) || (A2 == d2 && tb);                         \
  }
#define STEP_P(r) CMP3(ROR(b0, r), ROR(b1, r), ROR(b2, r), ROR(sub, r))
#define STEP_S(r) CMP3(ROR(s0, r), ROR(s1, r), ROR(s2, r), ROR(jsw, r))

  STEP_P(1)  STEP_P(2)  STEP_P(3)  STEP_P(4)  STEP_P(5)
  STEP_P(6)  STEP_P(7)  STEP_P(8)  STEP_P(9)  STEP_P(10)
  STEP_P(11) STEP_P(12) STEP_P(13) STEP_P(14) STEP_P(15)
  CMP3(s0, s1, s2, jsw)  // swapped copy, rotation 0
  STEP_S(1)  STEP_S(2)  STEP_S(3)  STEP_S(4)  STEP_S(5)
  STEP_S(6)  STEP_S(7)  STEP_S(8)  STEP_S(9)  STEP_S(10)
  STEP_S(11) STEP_S(12) STEP_S(13) STEP_S(14) STEP_S(15)
#undef STEP_S
#undef STEP_P
#undef CMP3

  // push src to lane hbase/4 + rank; ranks unique per half
  int p0 = __builtin_amdgcn_ds_permute(hbase + (c0 << 2), src0);
  int p1 = __builtin_amdgcn_ds_permute(hbase + (c1 << 2), src1);
  int p2 = __builtin_amdgcn_ds_permute(hbase + (c2 << 2), src2);

  // Phase 3: merged gather — fp8 rows (1 dword/lane), f32 accumulation
  float a00 = 0.f, a01 = 0.f, a02 = 0.f, a03 = 0.f;
  float a10 = 0.f, a11 = 0.f, a12 = 0.f, a13 = 0.f;
  float a20 = 0.f, a21 = 0.f, a22 = 0.f, a23 = 0.f;
#pragma unroll
  for (int t = 0; t < NSEL; ++t) {
    int r0 = __builtin_amdgcn_ds_bpermute(hbase + 4 * t, p0);
    int r1 = __builtin_amdgcn_ds_bpermute(hbase + 4 * t, p1);
    int r2 = __builtin_amdgcn_ds_bpermute(hbase + 4 * t, p2);
    unsigned int w0 =
        *(const unsigned int*)(feat8 + ((unsigned)r0 << 7) + (sub << 2));
    unsigned int w1 =
        *(const unsigned int*)(feat8 + ((unsigned)r1 << 7) + (sub << 2));
    unsigned int w2 =
        *(const unsigned int*)(feat8 + ((unsigned)r2 << 7) + (sub << 2));
    floatx2 l0 = __builtin_amdgcn_cvt_pk_f32_fp8(w0, false);
    floatx2 h0 = __builtin_amdgcn_cvt_pk_f32_fp8(w0, true);
    floatx2 l1 = __builtin_amdgcn_cvt_pk_f32_fp8(w1, false);
    floatx2 h1 = __builtin_amdgcn_cvt_pk_f32_fp8(w1, true);
    floatx2 l2 = __builtin_amdgcn_cvt_pk_f32_fp8(w2, false);
    floatx2 h2 = __builtin_amdgcn_cvt_pk_f32_fp8(w2, true);
    a00 += l0.x; a01 += l0.y; a02 += h0.x; a03 += h0.y;
    a10 += l1.x; a11 += l1.y; a12 += h1.x; a13 += h1.y;
    a20 += l2.x; a21 += l2.y; a22 += h2.x; a23 += h2.y;
  }
  acc.x += 0.5f * fast_tanh(a00 * (1.f / NSEL));
  acc.y += 0.5f * fast_tanh(a01 * (1.f / NSEL));
  acc.z += 0.5f * fast_tanh(a02 * (1.f / NSEL));
  acc.w += 0.5f * fast_tanh(a03 * (1.f / NSEL));
  acc.x += 0.5f * fast_tanh(a10 * (1.f / NSEL));
  acc.y += 0.5f * fast_tanh(a11 * (1.f / NSEL));
  acc.z += 0.5f * fast_tanh(a12 * (1.f / NSEL));
  acc.w += 0.5f * fast_tanh(a13 * (1.f / NSEL));
  acc.x += 0.5f * fast_tanh(a20 * (1.f / NSEL));
  acc.y += 0.5f * fast_tanh(a21 * (1.f / NSEL));
  acc.z += 0.5f * fast_tanh(a22 * (1.f / NSEL));
  acc.w += 0.5f * fast_tanh(a23 * (1.f / NSEL));

  acc.x = fast_tanh(acc.x);
  acc.y = fast_tanh(acc.y);
  acc.z = fast_tanh(acc.z);
  acc.w = fast_tanh(acc.w);
  uint2 p;
  p.x = pack_h2(acc.x, acc.y);
  p.y = pack_h2(acc.z, acc.w);
  *(uint2*)(hfw + n * (D / 2) + sub * 2) = p;  // fp16 h row, 256 B/node
}

// Kernel C: out[50000x64] = h[50000x128] @ W_lin + b_lin via fp16 MFMA.
// h read fp16-packed from d_out rows, overwritten in place (each wave reads
// its full 16-row tile before storing). A: m=lane&15, k=(lane>>4)*8+j.
// C: n=lane&15, m=(lane>>4)*4+reg (m89-verified).
__global__ __launch_bounds__(256) void gemm_kernel(
    const unsigned int* __restrict__ hfw, const float* __restrict__ Wl,
    const float* __restrict__ bl, float* __restrict__ out) {
  __shared__ _Float16 sB[16 * 64 * 8];  // 16 KB: [kk*4+nt][lane][8]

  for (int w = threadIdx.x; w < 4096; w += blockDim.x) {
    int f = w >> 8, l = (w >> 2) & 63, j2 = w & 3;
    int kk = f >> 2, nt = f & 3;
    int k = kk * 32 + ((l >> 4) << 3) + 2 * j2;
    int nn = nt * 16 + (l & 15);
    ((unsigned int*)sB)[w] = pack_h2(Wl[k * DOUT + nn], Wl[(k + 1) * DOUT + nn]);
  }
  __syncthreads();

  const int lane = threadIdx.x & 63;
  const int tile = blockIdx.x * 4 + (threadIdx.x >> 6);
  if (tile >= NTILES) return;
  const int m0 = tile * 16;

  floatx4 acc[4];
#pragma unroll
  for (int nt = 0; nt < 4; ++nt) {
    float bn = bl[nt * 16 + (lane & 15)];
    acc[nt] = (floatx4){bn, bn, bn, bn};
  }
  const _Float16* hf = (const _Float16*)hfw;
#pragma unroll
  for (int kk = 0; kk < 4; ++kk) {
    half8 a = *(const half8*)(hf + (size_t)(m0 + (lane & 15)) * D + kk * 32 +
                              ((lane >> 4) << 3));
#pragma unroll
    for (int nt = 0; nt < 4; ++nt) {
      half8 bfr = *(const half8*)(sB + ((kk * 4 + nt) * 64 + lane) * 8);
      acc[nt] = __builtin_amdgcn_mfma_f32_16x16x32_f16(a, bfr, acc[nt], 0, 0, 0);
    }
  }
#pragma unroll
  for (int nt = 0; nt < 4; ++nt) {
#pragma unroll
    for (int r = 0; r < 4; ++r) {
      int m = m0 + ((lane >> 4) << 2) + r;
      out[(size_t)m * DOUT + nt * 16 + (lane & 15)] = acc[nt][r];
    }
  }
}

extern "C" void kernel_launch(void* const* d_in, const int* in_sizes, int n_in,
                              void* d_out, int out_size, void* d_ws,
                              size_t ws_size, hipStream_t stream) {
  const float* feat = (const float*)d_in[0];
  const float* Wm = (const float*)d_in[1];
  const float* bm = (const float*)d_in[2];
  const float* Wl = (const float*)d_in[3];
  const float* bl = (const float*)d_in[4];
  const int* nbr0 = (const int*)d_in[5];
  const int* nbr1 = (const int*)d_in[6];
  const int* nbr2 = (const int*)d_in[7];
  float* out = (float*)d_out;
  float2* mlp2 = (float2*)d_ws;                                       // 400 KB
  unsigned char* feat8 = (unsigned char*)d_ws + (512 << 10);          // 6.4 MB

  mlp_kernel<<<N_NODES / 8, 256, 0, stream>>>(feat, Wm, bm, mlp2, feat8);
  care_kernel<<<N_NODES / 8, 256, 0, stream>>>(feat, feat8, mlp2, nbr0, nbr1,
                                               nbr2, (unsigned int*)d_out);
  gemm_kernel<<<(NTILES + 3) / 4, 256, 0, stream>>>((const unsigned int*)d_out,
                                                    Wl, bl, out);
}

// Round 11
// 67.126 us; speedup vs baseline: 1.5104x; 1.1184x over previous
//
#include <hip/hip_runtime.h>
#include <hip/hip_fp16.h>

#define N_NODES 50000
#define K 32
#define NSEL 16
#define D 128
#define DOUT 64
#define NTILES (N_NODES / 16)  // 3125 MFMA node-tiles

typedef __attribute__((ext_vector_type(8))) _Float16 half8;
typedef __attribute__((ext_vector_type(4))) float floatx4;
typedef __attribute__((ext_vector_type(2))) float floatx2;

__device__ __forceinline__ unsigned int pack_h2(float a, float b) {
  union { __half2 h; unsigned int u; } c;
  c.h = __floats2half2_rn(a, b);
  return c.u;
}
__device__ __forceinline__ float fast_tanh(float x) {
  // 1 - 2/(1+e^{2x}): mul, exp, add, rcp, mul, sub. Exact at +/-inf.
  float e = __expf(2.f * x);
  return 1.f - __fdividef(2.f, 1.f + e);
}

// Kernel A: mlp2[n] = tanh(feat[n] @ W_mlp + b_mlp) (C=2), feat8 = fp8(feat).
// TWO nodes per wave. libm tanhf — mlp2 feeds top-k; fast tanh flips ties.
__global__ __launch_bounds__(256) void mlp_kernel(
    const float* __restrict__ feat, const float* __restrict__ Wm,
    const float* __restrict__ bm, float2* __restrict__ mlp2,
    unsigned char* __restrict__ feat8 /* [N][D] fp8 e4m3, 128 B rows */) {
  const int wid = (blockIdx.x * blockDim.x + threadIdx.x) >> 6;  // 0..24999
  const int lane = threadIdx.x & 63;
  const int sub = lane & 31;
  const int n = wid * 2 + (lane >> 5);

  float4 f = *(const float4*)(feat + (size_t)n * D + sub * 4);
  float4 w01 = *(const float4*)(Wm + sub * 8);
  float4 w23 = *(const float4*)(Wm + sub * 8 + 4);
  float p0 = f.x * w01.x + f.y * w01.z + f.z * w23.x + f.w * w23.z;
  float p1 = f.x * w01.y + f.y * w01.w + f.z * w23.y + f.w * w23.w;
#pragma unroll
  for (int off = 16; off; off >>= 1) {  // stays within the 32-lane half
    p0 += __shfl_xor(p0, off);
    p1 += __shfl_xor(p1, off);
  }
  // fp8 e4m3 copy of feat (RNE pack, 4 dims -> 1 dword per lane)
  int pk8 = __builtin_amdgcn_cvt_pk_fp8_f32(f.x, f.y, 0, false);
  pk8 = __builtin_amdgcn_cvt_pk_fp8_f32(f.z, f.w, pk8, true);
  *(unsigned int*)(feat8 + ((size_t)n << 7) + (sub << 2)) = (unsigned int)pk8;
  if (sub == 0) {
    mlp2[n] = make_float2(tanhf(p0 + bm[0]), tanhf(p1 + bm[1]));
  }
}

// Kernel B: TWO nodes per wave, 3 etypes merged.
// Rank: u64 key compare  key=(bits(d)<<32)|j  — lexicographic < is EXACTLY
// (d_j<d_i)||(d_j==d_i&&j<i) since d>=0. Distance bits broadcast via
// ds_bpermute (DS pipe has headroom; VALU is the bottleneck).
// Gather: fp8 rows, floatx2 (v_pk_add_f32) f32 accumulation.
__global__ __launch_bounds__(256) void care_kernel(
    const float* __restrict__ feat, const unsigned char* __restrict__ feat8,
    const float2* __restrict__ mlp2, const int* __restrict__ nbr0,
    const int* __restrict__ nbr1, const int* __restrict__ nbr2,
    unsigned int* __restrict__ hfw /* aliases d_out; [N][64] words */) {
  const int lane = threadIdx.x & 63;
  const int sub = lane & 31;
  const int hbase = (lane & 32) << 2;  // DS byte addr of this half's lane 0
  const int wid = (blockIdx.x * blockDim.x + threadIdx.x) >> 6;  // 0..24999
  const int n = wid * 2 + (lane >> 5);

  const float2 my = mlp2[n];
  float4 acc = *(const float4*)(feat + (size_t)n * D + sub * 4);  // residual

  // Phase 1: all edge ids + their mlp2 rows (6 loads in flight)
  const int src0 = nbr0[n * K + sub];
  const int src1 = nbr1[n * K + sub];
  const int src2 = nbr2[n * K + sub];
  const float2 mh0 = mlp2[src0];
  const float2 mh1 = mlp2[src1];
  const float2 mh2 = mlp2[src2];
  const float d0 = fabsf(mh0.x - my.x) + fabsf(mh0.y - my.y);
  const float d1 = fabsf(mh1.x - my.x) + fabsf(mh1.y - my.y);
  const float d2 = fabsf(mh2.x - my.x) + fabsf(mh2.y - my.y);

  // Phase 2: rank via u64 lexicographic keys (bit-exact top_k tie-break)
  const int b0 = __float_as_int(d0);
  const int b1 = __float_as_int(d1);
  const int b2 = __float_as_int(d2);
  const unsigned long long ki0 =
      ((unsigned long long)(unsigned)b0 << 32) | (unsigned)sub;
  const unsigned long long ki1 =
      ((unsigned long long)(unsigned)b1 << 32) | (unsigned)sub;
  const unsigned long long ki2 =
      ((unsigned long long)(unsigned)b2 << 32) | (unsigned)sub;
  int c0 = 0, c1 = 0, c2 = 0;
#pragma unroll
  for (int j = 0; j < K; ++j) {
    const int aj = hbase + 4 * j;
    const unsigned a0 = (unsigned)__builtin_amdgcn_ds_bpermute(aj, b0);
    const unsigned a1 = (unsigned)__builtin_amdgcn_ds_bpermute(aj, b1);
    const unsigned a2 = (unsigned)__builtin_amdgcn_ds_bpermute(aj, b2);
    c0 += (((unsigned long long)a0 << 32) | (unsigned)j) < ki0;
    c1 += (((unsigned long long)a1 << 32) | (unsigned)j) < ki1;
    c2 += (((unsigned long long)a2 << 32) | (unsigned)j) < ki2;
  }

  // push src to lane hbase/4 + rank; ranks unique per half
  int p0 = __builtin_amdgcn_ds_permute(hbase + (c0 << 2), src0);
  int p1 = __builtin_amdgcn_ds_permute(hbase + (c1 << 2), src1);
  int p2 = __builtin_amdgcn_ds_permute(hbase + (c2 << 2), src2);

  // Phase 3: merged gather — fp8 rows (1 dword/lane), packed f32 accumulation
  const unsigned sub4 = (unsigned)sub << 2;
  floatx2 A00 = {0.f, 0.f}, A01 = {0.f, 0.f};
  floatx2 A10 = {0.f, 0.f}, A11 = {0.f, 0.f};
  floatx2 A20 = {0.f, 0.f}, A21 = {0.f, 0.f};
#pragma unroll
  for (int t = 0; t < NSEL; ++t) {
    const int at = hbase + 4 * t;
    int r0 = __builtin_amdgcn_ds_bpermute(at, p0);
    int r1 = __builtin_amdgcn_ds_bpermute(at, p1);
    int r2 = __builtin_amdgcn_ds_bpermute(at, p2);
    unsigned int w0 = *(const unsigned int*)(feat8 + (((unsigned)r0 << 7) | sub4));
    unsigned int w1 = *(const unsigned int*)(feat8 + (((unsigned)r1 << 7) | sub4));
    unsigned int w2 = *(const unsigned int*)(feat8 + (((unsigned)r2 << 7) | sub4));
    A00 += __builtin_amdgcn_cvt_pk_f32_fp8(w0, false);
    A01 += __builtin_amdgcn_cvt_pk_f32_fp8(w0, true);
    A10 += __builtin_amdgcn_cvt_pk_f32_fp8(w1, false);
    A11 += __builtin_amdgcn_cvt_pk_f32_fp8(w1, true);
    A20 += __builtin_amdgcn_cvt_pk_f32_fp8(w2, false);
    A21 += __builtin_amdgcn_cvt_pk_f32_fp8(w2, true);
  }
  acc.x += 0.5f * fast_tanh(A00.x * (1.f / NSEL));
  acc.y += 0.5f * fast_tanh(A00.y * (1.f / NSEL));
  acc.z += 0.5f * fast_tanh(A01.x * (1.f / NSEL));
  acc.w += 0.5f * fast_tanh(A01.y * (1.f / NSEL));
  acc.x += 0.5f * fast_tanh(A10.x * (1.f / NSEL));
  acc.y += 0.5f * fast_tanh(A10.y * (1.f / NSEL));
  acc.z += 0.5f * fast_tanh(A11.x * (1.f / NSEL));
  acc.w += 0.5f * fast_tanh(A11.y * (1.f / NSEL));
  acc.x += 0.5f * fast_tanh(A20.x * (1.f / NSEL));
  acc.y += 0.5f * fast_tanh(A20.y * (1.f / NSEL));
  acc.z += 0.5f * fast_tanh(A21.x * (1.f / NSEL));
  acc.w += 0.5f * fast_tanh(A21.y * (1.f / NSEL));

  acc.x = fast_tanh(acc.x);
  acc.y = fast_tanh(acc.y);
  acc.z = fast_tanh(acc.z);
  acc.w = fast_tanh(acc.w);
  uint2 p;
  p.x = pack_h2(acc.x, acc.y);
  p.y = pack_h2(acc.z, acc.w);
  *(uint2*)(hfw + n * (D / 2) + sub * 2) = p;  // fp16 h row, 256 B/node
}

// Kernel C: out[50000x64] = h[50000x128] @ W_lin + b_lin via fp16 MFMA.
// h read fp16-packed from d_out rows, overwritten in place (each wave reads
// its full 16-row tile before storing). A: m=lane&15, k=(lane>>4)*8+j.
// C: n=lane&15, m=(lane>>4)*4+reg (m89-verified).
__global__ __launch_bounds__(256) void gemm_kernel(
    const unsigned int* __restrict__ hfw, const float* __restrict__ Wl,
    const float* __restrict__ bl, float* __restrict__ out) {
  __shared__ _Float16 sB[16 * 64 * 8];  // 16 KB: [kk*4+nt][lane][8]

  for (int w = threadIdx.x; w < 4096; w += blockDim.x) {
    int f = w >> 8, l = (w >> 2) & 63, j2 = w & 3;
    int kk = f >> 2, nt = f & 3;
    int k = kk * 32 + ((l >> 4) << 3) + 2 * j2;
    int nn = nt * 16 + (l & 15);
    ((unsigned int*)sB)[w] = pack_h2(Wl[k * DOUT + nn], Wl[(k + 1) * DOUT + nn]);
  }
  __syncthreads();

  const int lane = threadIdx.x & 63;
  const int tile = blockIdx.x * 4 + (threadIdx.x >> 6);
  if (tile >= NTILES) return;
  const int m0 = tile * 16;

  floatx4 acc[4];
#pragma unroll
  for (int nt = 0; nt < 4; ++nt) {
    float bn = bl[nt * 16 + (lane & 15)];
    acc[nt] = (floatx4){bn, bn, bn, bn};
  }
  const _Float16* hf = (const _Float16*)hfw;
#pragma unroll
  for (int kk = 0; kk < 4; ++kk) {
    half8 a = *(const half8*)(hf + (size_t)(m0 + (lane & 15)) * D + kk * 32 +
                              ((lane >> 4) << 3));
#pragma unroll
    for (int nt = 0; nt < 4; ++nt) {
      half8 bfr = *(const half8*)(sB + ((kk * 4 + nt) * 64 + lane) * 8);
      acc[nt] = __builtin_amdgcn_mfma_f32_16x16x32_f16(a, bfr, acc[nt], 0, 0, 0);
    }
  }
#pragma unroll
  for (int nt = 0; nt < 4; ++nt) {
#pragma unroll
    for (int r = 0; r < 4; ++r) {
      int m = m0 + ((lane >> 4) << 2) + r;
      out[(size_t)m * DOUT + nt * 16 + (lane & 15)] = acc[nt][r];
    }
  }
}

extern "C" void kernel_launch(void* const* d_in, const int* in_sizes, int n_in,
                              void* d_out, int out_size, void* d_ws,
                              size_t ws_size, hipStream_t stream) {
  const float* feat = (const float*)d_in[0];
  const float* Wm = (const float*)d_in[1];
  const float* bm = (const float*)d_in[2];
  const float* Wl = (const float*)d_in[3];
  const float* bl = (const float*)d_in[4];
  const int* nbr0 = (const int*)d_in[5];
  const int* nbr1 = (const int*)d_in[6];
  const int* nbr2 = (const int*)d_in[7];
  float* out = (float*)d_out;
  float2* mlp2 = (float2*)d_ws;                                       // 400 KB
  unsigned char* feat8 = (unsigned char*)d_ws + (512 << 10);          // 6.4 MB

  mlp_kernel<<<N_NODES / 8, 256, 0, stream>>>(feat, Wm, bm, mlp2, feat8);
  care_kernel<<<N_NODES / 8, 256, 0, stream>>>(feat, feat8, mlp2, nbr0, nbr1,
                                               nbr2, (unsigned int*)d_out);
  gemm_kernel<<<(NTILES + 3) / 4, 256, 0, stream>>>((const unsigned int*)d_out,
                                                    Wl, bl, out);
}